// Round 3
// baseline (1415.364 us; speedup 1.0000x reference)
//
#include <hip/hip_runtime.h>

#define HD 64
#define ROW 256  // 4 slots * 64 lanes, bf16 elements per node row

// ---------------------------------------------------------------------------
// bf16 helpers (manual, round-to-nearest-even-ish)
// ---------------------------------------------------------------------------
__device__ inline unsigned short f2bf(float f) {
    unsigned u = __builtin_bit_cast(unsigned, f);
    u += 0x7FFFu + ((u >> 16) & 1u);
    return (unsigned short)(u >> 16);
}
__device__ inline float bf2f(unsigned short h) {
    unsigned u = ((unsigned)h) << 16;
    return __builtin_bit_cast(float, u);
}

// ---------------------------------------------------------------------------
// CSR construction helpers
// ---------------------------------------------------------------------------

__global__ void k_count(const int* __restrict__ s, const int* __restrict__ t, int E,
                        unsigned* __restrict__ ds, unsigned* __restrict__ dt) {
    int i = blockIdx.x * blockDim.x + threadIdx.x;
    int st = gridDim.x * blockDim.x;
    for (; i < E; i += st) {
        atomicAdd(ds + s[i], 1u);
        atomicAdd(dt + t[i], 1u);
    }
}

__global__ void k_rs(const unsigned* __restrict__ d, float* __restrict__ r, int n) {
    int i = blockIdx.x * blockDim.x + threadIdx.x;
    if (i < n) {
        unsigned v = d[i];
        r[i] = v ? 1.0f / sqrtf((float)v) : 0.0f;
    }
}

// Row offsets without a prefix scan: ranges need to be disjoint, not ordered.
__global__ void k_off(const unsigned* __restrict__ deg, int n, unsigned* __restrict__ off,
                      unsigned* __restrict__ cur, unsigned* __restrict__ cnt) {
    int i = blockIdx.x * blockDim.x + threadIdx.x;
    if (i < n) {
        unsigned o = atomicAdd(cnt, deg[i]);
        off[i] = o;
        cur[i] = o;
    }
}

__global__ void k_fill(const int* __restrict__ s, const int* __restrict__ t, int E,
                       unsigned* __restrict__ cur, int* __restrict__ col) {
    int i = blockIdx.x * blockDim.x + threadIdx.x;
    int st = gridDim.x * blockDim.x;
    for (; i < E; i += st) {
        int p = (int)atomicAdd(cur + t[i], 1u);
        col[p] = s[i];
    }
}

__global__ void k_sentinel(float* __restrict__ out, int n, float val) {
    int i = blockIdx.x * blockDim.x + threadIdx.x;
    if (i < n) out[i] = val;
}

// ---------------------------------------------------------------------------
// Layer-1 pull kernels. One wave (64 lanes) per destination row; lane = h.
// L1 outputs stored bf16 packed [node][64][4]: elem = node*256 + lane*4 + slot,
// so layer-2 gathers are one ushort4 (8B) per lane per row.
// ---------------------------------------------------------------------------

// user <- spot over us_r (all 4 branches), div=1
__global__ void k_l1_user(const int* __restrict__ col, const unsigned* __restrict__ off,
                          const unsigned* __restrict__ deg,
                          const float* __restrict__ rs_src, const float* __restrict__ rs_dst,
                          const float* __restrict__ s1, const float* __restrict__ s2,
                          const float* __restrict__ s3, const float* __restrict__ s4,
                          unsigned short* __restrict__ out, int n) {
    int w = (blockIdx.x * blockDim.x + threadIdx.x) >> 6;
    int lane = threadIdx.x & 63;
    if (w >= n) return;
    unsigned o = off[w], d = deg[w];
    float a0 = 0, a1 = 0, a2 = 0, a3 = 0;
    for (unsigned e = 0; e < d; ++e) {
        int s = col[o + e];
        float sc = rs_src[s];
        int b = s * HD + lane;
        a0 = fmaf(s1[b], sc, a0);
        a1 = fmaf(s2[b], sc, a1);
        a2 = fmaf(s3[b], sc, a2);
        a3 = fmaf(s4[b], sc, a3);
    }
    float rd = rs_dst[w];
    ushort4 pk;
    pk.x = f2bf(fmaxf(a0 * rd, 0.f));
    pk.y = f2bf(fmaxf(a1 * rd, 0.f));
    pk.z = f2bf(fmaxf(a2 * rd, 0.f));
    pk.w = f2bf(fmaxf(a3 * rd, 0.f));
    *reinterpret_cast<ushort4*>(out + w * ROW + lane * 4) = pk;
}

// spot <- user (us_f, all branches) + cat (sc_r, b2/b4) + city (sci_r, b3/b4)
__global__ void k_l1_spot(
    const int* __restrict__ colU, const unsigned* __restrict__ offU, const unsigned* __restrict__ degU,
    const float* __restrict__ rsU_src, const float* __restrict__ rsU_dst,
    const int* __restrict__ colC, const unsigned* __restrict__ offC, const unsigned* __restrict__ degC,
    const float* __restrict__ rsC_src, const float* __restrict__ rsC_dst,
    const int* __restrict__ colI, const unsigned* __restrict__ offI, const unsigned* __restrict__ degI,
    const float* __restrict__ rsI_src, const float* __restrict__ rsI_dst,
    const float* __restrict__ u1, const float* __restrict__ u2,
    const float* __restrict__ u3, const float* __restrict__ u4,
    const float* __restrict__ c2, const float* __restrict__ c4,
    const float* __restrict__ i3, const float* __restrict__ i4,
    unsigned short* __restrict__ out, int n) {
    int w = (blockIdx.x * blockDim.x + threadIdx.x) >> 6;
    int lane = threadIdx.x & 63;
    if (w >= n) return;
    float a0 = 0, a1 = 0, a2 = 0, a3 = 0;
    {
        unsigned o = offU[w], d = degU[w];
        for (unsigned e = 0; e < d; ++e) {
            int s = colU[o + e];
            float sc = rsU_src[s];
            int b = s * HD + lane;
            a0 = fmaf(u1[b], sc, a0);
            a1 = fmaf(u2[b], sc, a1);
            a2 = fmaf(u3[b], sc, a2);
            a3 = fmaf(u4[b], sc, a3);
        }
        float rd = rsU_dst[w];
        a0 *= rd; a1 *= rd; a2 *= rd; a3 *= rd;
    }
    float cA = 0, cB = 0;
    {
        unsigned o = offC[w], d = degC[w];
        for (unsigned e = 0; e < d; ++e) {
            int s = colC[o + e];
            float sc = rsC_src[s];
            int b = s * HD + lane;
            cA = fmaf(c2[b], sc, cA);
            cB = fmaf(c4[b], sc, cB);
        }
        float rd = rsC_dst[w];
        cA *= rd; cB *= rd;
    }
    float iA = 0, iB = 0;
    {
        unsigned o = offI[w], d = degI[w];
        for (unsigned e = 0; e < d; ++e) {
            int s = colI[o + e];
            float sc = rsI_src[s];
            int b = s * HD + lane;
            iA = fmaf(i3[b], sc, iA);
            iB = fmaf(i4[b], sc, iB);
        }
        float rd = rsI_dst[w];
        iA *= rd; iB *= rd;
    }
    ushort4 pk;
    pk.x = f2bf(fmaxf(a0, 0.f));
    pk.y = f2bf(fmaxf((a1 + cA) * 0.5f, 0.f));
    pk.z = f2bf(fmaxf((a2 + iA) * 0.5f, 0.f));
    pk.w = f2bf(fmaxf((a3 + cB + iB) * (1.0f / 3.0f), 0.f));
    *reinterpret_cast<ushort4*>(out + w * ROW + lane * 4) = pk;
}

// category <- spot over sc_f (branches 2,4 -> slots 1,3), div=1
__global__ void k_l1_cat(const int* __restrict__ col, const unsigned* __restrict__ off,
                         const unsigned* __restrict__ deg,
                         const float* __restrict__ rs_src, const float* __restrict__ rs_dst,
                         const float* __restrict__ s2, const float* __restrict__ s4,
                         unsigned short* __restrict__ out, int n) {
    int w = (blockIdx.x * blockDim.x + threadIdx.x) >> 6;
    int lane = threadIdx.x & 63;
    if (w >= n) return;
    unsigned o = off[w], d = deg[w];
    float a1 = 0, a3 = 0;
    for (unsigned e = 0; e < d; ++e) {
        int s = col[o + e];
        float sc = rs_src[s];
        int b = s * HD + lane;
        a1 = fmaf(s2[b], sc, a1);
        a3 = fmaf(s4[b], sc, a3);
    }
    float rd = rs_dst[w];
    ushort4 pk;
    pk.x = 0;
    pk.y = f2bf(fmaxf(a1 * rd, 0.f));
    pk.z = 0;
    pk.w = f2bf(fmaxf(a3 * rd, 0.f));
    *reinterpret_cast<ushort4*>(out + w * ROW + lane * 4) = pk;
}

// city <- spot (sci_f) + pref (cp_r), branches 3,4 -> slots 2,3, div=2
__global__ void k_l1_city(const int* __restrict__ colS, const unsigned* __restrict__ offS,
                          const unsigned* __restrict__ degS,
                          const float* __restrict__ rsS_src, const float* __restrict__ rsS_dst,
                          const int* __restrict__ colP, const unsigned* __restrict__ offP,
                          const unsigned* __restrict__ degP,
                          const float* __restrict__ rsP_src, const float* __restrict__ rsP_dst,
                          const float* __restrict__ s3, const float* __restrict__ s4,
                          const float* __restrict__ p3, const float* __restrict__ p4,
                          unsigned short* __restrict__ out, int n) {
    int w = (blockIdx.x * blockDim.x + threadIdx.x) >> 6;
    int lane = threadIdx.x & 63;
    if (w >= n) return;
    float a2 = 0, a3 = 0;
    {
        unsigned o = offS[w], d = degS[w];
        for (unsigned e = 0; e < d; ++e) {
            int s = colS[o + e];
            float sc = rsS_src[s];
            int b = s * HD + lane;
            a2 = fmaf(s3[b], sc, a2);
            a3 = fmaf(s4[b], sc, a3);
        }
        float rd = rsS_dst[w];
        a2 *= rd; a3 *= rd;
    }
    float b2 = 0, b3 = 0;
    {
        unsigned o = offP[w], d = degP[w];
        for (unsigned e = 0; e < d; ++e) {
            int s = colP[o + e];
            float sc = rsP_src[s];
            int b = s * HD + lane;
            b2 = fmaf(p3[b], sc, b2);
            b3 = fmaf(p4[b], sc, b3);
        }
        float rd = rsP_dst[w];
        b2 *= rd; b3 *= rd;
    }
    ushort4 pk;
    pk.x = 0;
    pk.y = 0;
    pk.z = f2bf(fmaxf((a2 + b2) * 0.5f, 0.f));
    pk.w = f2bf(fmaxf((a3 + b3) * 0.5f, 0.f));
    *reinterpret_cast<ushort4*>(out + w * ROW + lane * 4) = pk;
}

// ---------------------------------------------------------------------------
// Layer-2 + mean-over-layers + linear head, fused. L2 never materialized.
// ---------------------------------------------------------------------------

__global__ void k_user_out(const int* __restrict__ col, const unsigned* __restrict__ off,
                           const unsigned* __restrict__ deg,
                           const float* __restrict__ rs_src, const float* __restrict__ rs_dst,
                           const unsigned short* __restrict__ l1spot,
                           const unsigned short* __restrict__ l1user,
                           const float* __restrict__ x1, const float* __restrict__ x2,
                           const float* __restrict__ x3, const float* __restrict__ x4,
                           const float* __restrict__ wlin, const float* __restrict__ blin,
                           float* __restrict__ out, int n) {
    int u = (blockIdx.x * blockDim.x + threadIdx.x) >> 6;
    int lane = threadIdx.x & 63;
    if (u >= n) return;
    float a0 = 0, a1 = 0, a2 = 0, a3 = 0;
    unsigned o = off[u], d = deg[u];
    for (unsigned e = 0; e < d; ++e) {
        int s = col[o + e];
        float sc = rs_src[s];
        ushort4 v = *reinterpret_cast<const ushort4*>(l1spot + s * ROW + lane * 4);
        a0 = fmaf(bf2f(v.x), sc, a0);
        a1 = fmaf(bf2f(v.y), sc, a1);
        a2 = fmaf(bf2f(v.z), sc, a2);
        a3 = fmaf(bf2f(v.w), sc, a3);
    }
    float rd = rs_dst[u];
    a0 = fmaxf(a0 * rd, 0.f);
    a1 = fmaxf(a1 * rd, 0.f);
    a2 = fmaxf(a2 * rd, 0.f);
    a3 = fmaxf(a3 * rd, 0.f);
    int xb = u * HD + lane;
    ushort4 lv = *reinterpret_cast<const ushort4*>(l1user + u * ROW + lane * 4);
    const float third = 1.0f / 3.0f;
    float m0 = (x1[xb] + bf2f(lv.x) + a0) * third;
    float m1 = (x2[xb] + bf2f(lv.y) + a1) * third;
    float m2 = (x3[xb] + bf2f(lv.z) + a2) * third;
    float m3 = (x4[xb] + bf2f(lv.w) + a3) * third;
    float p = m0 * wlin[lane] + m1 * wlin[HD + lane] + m2 * wlin[2 * HD + lane] +
              m3 * wlin[3 * HD + lane];
#pragma unroll
    for (int ofs = 32; ofs; ofs >>= 1) p += __shfl_xor(p, ofs, 64);
    if (lane == 0) out[u] = p + blin[0];
}

__global__ void k_spot_out(
    const int* __restrict__ colU, const unsigned* __restrict__ offU, const unsigned* __restrict__ degU,
    const float* __restrict__ rsU_src, const float* __restrict__ rsU_dst,
    const int* __restrict__ colC, const unsigned* __restrict__ offC, const unsigned* __restrict__ degC,
    const float* __restrict__ rsC_src, const float* __restrict__ rsC_dst,
    const int* __restrict__ colI, const unsigned* __restrict__ offI, const unsigned* __restrict__ degI,
    const float* __restrict__ rsI_src, const float* __restrict__ rsI_dst,
    const unsigned short* __restrict__ l1user, const unsigned short* __restrict__ l1cat,
    const unsigned short* __restrict__ l1city, const unsigned short* __restrict__ l1spot,
    const float* __restrict__ x1, const float* __restrict__ x2,
    const float* __restrict__ x3, const float* __restrict__ x4,
    const float* __restrict__ wlin, const float* __restrict__ blin,
    float* __restrict__ out, int n) {
    int w = (blockIdx.x * blockDim.x + threadIdx.x) >> 6;
    int lane = threadIdx.x & 63;
    if (w >= n) return;
    float a0 = 0, a1 = 0, a2 = 0, a3 = 0;
    {
        unsigned o = offU[w], d = degU[w];
        for (unsigned e = 0; e < d; ++e) {
            int s = colU[o + e];
            float sc = rsU_src[s];
            ushort4 v = *reinterpret_cast<const ushort4*>(l1user + s * ROW + lane * 4);
            a0 = fmaf(bf2f(v.x), sc, a0);
            a1 = fmaf(bf2f(v.y), sc, a1);
            a2 = fmaf(bf2f(v.z), sc, a2);
            a3 = fmaf(bf2f(v.w), sc, a3);
        }
        float rd = rsU_dst[w];
        a0 *= rd; a1 *= rd; a2 *= rd; a3 *= rd;
    }
    float cA = 0, cB = 0;
    {
        unsigned o = offC[w], d = degC[w];
        for (unsigned e = 0; e < d; ++e) {
            int s = colC[o + e];
            float sc = rsC_src[s];
            ushort4 v = *reinterpret_cast<const ushort4*>(l1cat + s * ROW + lane * 4);
            cA = fmaf(bf2f(v.y), sc, cA);
            cB = fmaf(bf2f(v.w), sc, cB);
        }
        float rd = rsC_dst[w];
        cA *= rd; cB *= rd;
    }
    float iA = 0, iB = 0;
    {
        unsigned o = offI[w], d = degI[w];
        for (unsigned e = 0; e < d; ++e) {
            int s = colI[o + e];
            float sc = rsI_src[s];
            ushort4 v = *reinterpret_cast<const ushort4*>(l1city + s * ROW + lane * 4);
            iA = fmaf(bf2f(v.z), sc, iA);
            iB = fmaf(bf2f(v.w), sc, iB);
        }
        float rd = rsI_dst[w];
        iA *= rd; iB *= rd;
    }
    float L0 = fmaxf(a0, 0.f);
    float L1 = fmaxf((a1 + cA) * 0.5f, 0.f);
    float L2 = fmaxf((a2 + iA) * 0.5f, 0.f);
    float L3 = fmaxf((a3 + cB + iB) * (1.0f / 3.0f), 0.f);
    int xb = w * HD + lane;
    ushort4 lv = *reinterpret_cast<const ushort4*>(l1spot + w * ROW + lane * 4);
    const float third = 1.0f / 3.0f;
    float m0 = (x1[xb] + bf2f(lv.x) + L0) * third;
    float m1 = (x2[xb] + bf2f(lv.y) + L1) * third;
    float m2 = (x3[xb] + bf2f(lv.z) + L2) * third;
    float m3 = (x4[xb] + bf2f(lv.w) + L3) * third;
    float p = m0 * wlin[lane] + m1 * wlin[HD + lane] + m2 * wlin[2 * HD + lane] +
              m3 * wlin[3 * HD + lane];
#pragma unroll
    for (int ofs = 32; ofs; ofs >>= 1) p += __shfl_xor(p, ofs, 64);
    if (lane == 0) out[w] = p + blin[0];
}

// ---------------------------------------------------------------------------

static inline unsigned cdivu(unsigned a, unsigned b) { return (a + b - 1) / b; }

extern "C" void kernel_launch(void* const* d_in, const int* in_sizes, int n_in,
                              void* d_out, int out_size, void* d_ws, size_t ws_size,
                              hipStream_t stream) {
    const float* user1 = (const float*)d_in[0];
    const float* spot1 = (const float*)d_in[1];
    const float* user2 = (const float*)d_in[2];
    const float* spot2 = (const float*)d_in[3];
    const float* cat2  = (const float*)d_in[4];
    const float* user3 = (const float*)d_in[5];
    const float* spot3 = (const float*)d_in[6];
    const float* city3 = (const float*)d_in[7];
    const float* pref3 = (const float*)d_in[8];
    const float* user4 = (const float*)d_in[9];
    const float* spot4 = (const float*)d_in[10];
    const float* city4 = (const float*)d_in[11];
    const float* pref4 = (const float*)d_in[12];
    const float* cat4  = (const float*)d_in[13];
    const float* w_user = (const float*)d_in[14];
    const float* b_user = (const float*)d_in[15];
    const float* w_spot = (const float*)d_in[16];
    const float* b_spot = (const float*)d_in[17];
    const int* us_src  = (const int*)d_in[18];
    const int* us_dst  = (const int*)d_in[19];
    const int* sc_src  = (const int*)d_in[20];
    const int* sc_dst  = (const int*)d_in[21];
    const int* sci_src = (const int*)d_in[22];
    const int* sci_dst = (const int*)d_in[23];
    const int* cp_src  = (const int*)d_in[24];
    const int* cp_dst  = (const int*)d_in[25];

    const int NU = in_sizes[0] / HD, NS = in_sizes[1] / HD, NC = in_sizes[4] / HD;
    const int NCI = in_sizes[7] / HD, NP = in_sizes[8] / HD;
    const int EUS = in_sizes[18], ESC = in_sizes[20], ESCI = in_sizes[22], ECP = in_sizes[24];

    // ---- workspace bump allocator (256B aligned) ----
    char* wp = (char*)d_ws;
    auto alloc = [&](size_t bytes) -> void* {
        void* r = (void*)wp;
        wp += (bytes + 255) & ~(size_t)255;
        return r;
    };

    // degree block: 8 arrays + 7 counters, contiguous -> single memset
    const size_t nDeg = (size_t)NU + NS + NS + NC + NS + NCI + NCI + NP;
    unsigned* degBase = (unsigned*)alloc((nDeg + 8) * sizeof(unsigned));
    unsigned* ds_u   = degBase;                 // us: src user deg
    unsigned* dt_s   = ds_u + NU;               // us: dst spot deg
    unsigned* ds_ssc = dt_s + NS;               // sc: src spot deg
    unsigned* dt_c   = ds_ssc + NS;             // sc: dst cat deg
    unsigned* ds_ssi = dt_c + NC;               // sci: src spot deg
    unsigned* dt_ci  = ds_ssi + NS;             // sci: dst city deg
    unsigned* ds_cic = dt_ci + NCI;             // cp: src city deg
    unsigned* dt_p   = ds_cic + NCI;            // cp: dst pref deg
    unsigned* cnt    = dt_p + NP;               // 7 counters (padded to 8)

    float* rsBase = (float*)alloc(nDeg * sizeof(float));
    float* rs_ds_u   = rsBase;
    float* rs_dt_s   = rs_ds_u + NU;
    float* rs_ds_ssc = rs_dt_s + NS;
    float* rs_dt_c   = rs_ds_ssc + NS;
    float* rs_ds_ssi = rs_dt_c + NC;
    float* rs_dt_ci  = rs_ds_ssi + NS;
    float* rs_ds_cic = rs_dt_ci + NCI;
    float* rs_dt_p   = rs_ds_cic + NCI;

    // CSR offset/cursor/col arrays for the 7 needed pull directions
    unsigned* off_usf = (unsigned*)alloc(NS * 4);  unsigned* cur_usf = (unsigned*)alloc(NS * 4);
    unsigned* off_usr = (unsigned*)alloc((size_t)NU * 4); unsigned* cur_usr = (unsigned*)alloc((size_t)NU * 4);
    unsigned* off_scf = (unsigned*)alloc(NC * 4);  unsigned* cur_scf = (unsigned*)alloc(NC * 4);
    unsigned* off_scr = (unsigned*)alloc(NS * 4);  unsigned* cur_scr = (unsigned*)alloc(NS * 4);
    unsigned* off_sif = (unsigned*)alloc(NCI * 4); unsigned* cur_sif = (unsigned*)alloc(NCI * 4);
    unsigned* off_sir = (unsigned*)alloc(NS * 4);  unsigned* cur_sir = (unsigned*)alloc(NS * 4);
    unsigned* off_cpr = (unsigned*)alloc(NCI * 4); unsigned* cur_cpr = (unsigned*)alloc(NCI * 4);
    int* col_usf = (int*)alloc((size_t)EUS * 4);
    int* col_usr = (int*)alloc((size_t)EUS * 4);
    int* col_scf = (int*)alloc((size_t)ESC * 4);
    int* col_scr = (int*)alloc((size_t)ESC * 4);
    int* col_sif = (int*)alloc((size_t)ESCI * 4);
    int* col_sir = (int*)alloc((size_t)ESCI * 4);
    int* col_cpr = (int*)alloc((size_t)ECP * 4);

    // L1 feature planes, bf16 packed [node][64][4]
    unsigned short* l1_user = (unsigned short*)alloc((size_t)NU * ROW * 2);
    unsigned short* l1_spot = (unsigned short*)alloc((size_t)NS * ROW * 2);
    unsigned short* l1_cat  = (unsigned short*)alloc((size_t)NC * ROW * 2);
    unsigned short* l1_city = (unsigned short*)alloc((size_t)NCI * ROW * 2);

    float* outU = (float*)d_out;
    float* outS = outU + NU;

    // ---- ws guard: if workspace too small, emit readable sentinel, no ws writes
    size_t need = (size_t)(wp - (char*)d_ws);
    if (need > ws_size) {
        float val = 1000.0f + (float)(ws_size >> 20);
        k_sentinel<<<cdivu((unsigned)out_size, 256), 256, 0, stream>>>((float*)d_out, out_size, val);
        return;
    }

    // ---- build degrees / norms / CSRs ----
    hipMemsetAsync(degBase, 0, (nDeg + 8) * sizeof(unsigned), stream);
    k_count<<<1024, 256, 0, stream>>>(us_src, us_dst, EUS, ds_u, dt_s);
    k_count<<<256, 256, 0, stream>>>(sc_src, sc_dst, ESC, ds_ssc, dt_c);
    k_count<<<256, 256, 0, stream>>>(sci_src, sci_dst, ESCI, ds_ssi, dt_ci);
    k_count<<<32, 256, 0, stream>>>(cp_src, cp_dst, ECP, ds_cic, dt_p);
    k_rs<<<cdivu((unsigned)nDeg, 256), 256, 0, stream>>>(degBase, rsBase, (int)nDeg);

    k_off<<<cdivu(NS, 256), 256, 0, stream>>>(dt_s, NS, off_usf, cur_usf, cnt + 0);
    k_off<<<cdivu(NU, 256), 256, 0, stream>>>(ds_u, NU, off_usr, cur_usr, cnt + 1);
    k_off<<<cdivu(NC, 256), 256, 0, stream>>>(dt_c, NC, off_scf, cur_scf, cnt + 2);
    k_off<<<cdivu(NS, 256), 256, 0, stream>>>(ds_ssc, NS, off_scr, cur_scr, cnt + 3);
    k_off<<<cdivu(NCI, 256), 256, 0, stream>>>(dt_ci, NCI, off_sif, cur_sif, cnt + 4);
    k_off<<<cdivu(NS, 256), 256, 0, stream>>>(ds_ssi, NS, off_sir, cur_sir, cnt + 5);
    k_off<<<cdivu(NCI, 256), 256, 0, stream>>>(ds_cic, NCI, off_cpr, cur_cpr, cnt + 6);

    k_fill<<<1024, 256, 0, stream>>>(us_src, us_dst, EUS, cur_usf, col_usf);  // spot <- user
    k_fill<<<1024, 256, 0, stream>>>(us_dst, us_src, EUS, cur_usr, col_usr);  // user <- spot
    k_fill<<<256, 256, 0, stream>>>(sc_src, sc_dst, ESC, cur_scf, col_scf);   // cat  <- spot
    k_fill<<<256, 256, 0, stream>>>(sc_dst, sc_src, ESC, cur_scr, col_scr);   // spot <- cat
    k_fill<<<256, 256, 0, stream>>>(sci_src, sci_dst, ESCI, cur_sif, col_sif);// city <- spot
    k_fill<<<256, 256, 0, stream>>>(sci_dst, sci_src, ESCI, cur_sir, col_sir);// spot <- city
    k_fill<<<32, 256, 0, stream>>>(cp_dst, cp_src, ECP, cur_cpr, col_cpr);    // city <- pref

    // ---- layer 1 ----
    k_l1_user<<<cdivu(NU, 4), 256, 0, stream>>>(
        col_usr, off_usr, ds_u, rs_dt_s, rs_ds_u,
        spot1, spot2, spot3, spot4, l1_user, NU);
    k_l1_spot<<<cdivu(NS, 4), 256, 0, stream>>>(
        col_usf, off_usf, dt_s, rs_ds_u, rs_dt_s,
        col_scr, off_scr, ds_ssc, rs_dt_c, rs_ds_ssc,
        col_sir, off_sir, ds_ssi, rs_dt_ci, rs_ds_ssi,
        user1, user2, user3, user4, cat2, cat4, city3, city4, l1_spot, NS);
    k_l1_cat<<<cdivu(NC, 4), 256, 0, stream>>>(
        col_scf, off_scf, dt_c, rs_ds_ssc, rs_dt_c, spot2, spot4, l1_cat, NC);
    k_l1_city<<<cdivu(NCI, 4), 256, 0, stream>>>(
        col_sif, off_sif, dt_ci, rs_ds_ssi, rs_dt_ci,
        col_cpr, off_cpr, ds_cic, rs_dt_p, rs_ds_cic,
        spot3, spot4, pref3, pref4, l1_city, NCI);

    // ---- layer 2 fused with mean + linear head ----
    k_user_out<<<cdivu(NU, 4), 256, 0, stream>>>(
        col_usr, off_usr, ds_u, rs_dt_s, rs_ds_u,
        l1_spot, l1_user, user1, user2, user3, user4,
        w_user, b_user, outU, NU);
    k_spot_out<<<cdivu(NS, 4), 256, 0, stream>>>(
        col_usf, off_usf, dt_s, rs_ds_u, rs_dt_s,
        col_scr, off_scr, ds_ssc, rs_dt_c, rs_ds_ssc,
        col_sir, off_sir, ds_ssi, rs_dt_ci, rs_ds_ssi,
        l1_user, l1_cat, l1_city, l1_spot,
        spot1, spot2, spot3, spot4,
        w_spot, b_spot, outS, NS);

    (void)n_in; (void)out_size; (void)ws_size; (void)NP;
}

// Round 4
// 1405.871 us; speedup vs baseline: 1.0068x; 1.0068x over previous
//
#include <hip/hip_runtime.h>

#define HD 64
#define ROW 256  // 4 slots * 64 lanes, fp16 elements per node row

typedef _Float16 h16;
typedef __attribute__((ext_vector_type(4))) _Float16 h16x4;

// ---------------------------------------------------------------------------
// CSR construction helpers
// ---------------------------------------------------------------------------

__global__ void k_count(const int* __restrict__ s, const int* __restrict__ t, int E,
                        unsigned* __restrict__ ds, unsigned* __restrict__ dt) {
    int i = blockIdx.x * blockDim.x + threadIdx.x;
    int st = gridDim.x * blockDim.x;
    for (; i < E; i += st) {
        atomicAdd(ds + s[i], 1u);
        atomicAdd(dt + t[i], 1u);
    }
}

__global__ void k_rs(const unsigned* __restrict__ d, float* __restrict__ r, int n) {
    int i = blockIdx.x * blockDim.x + threadIdx.x;
    if (i < n) {
        unsigned v = d[i];
        r[i] = v ? 1.0f / sqrtf((float)v) : 0.0f;
    }
}

// Row offsets without a prefix scan: ranges need to be disjoint, not ordered.
__global__ void k_off(const unsigned* __restrict__ deg, int n, unsigned* __restrict__ off,
                      unsigned* __restrict__ cur, unsigned* __restrict__ cnt) {
    int i = blockIdx.x * blockDim.x + threadIdx.x;
    if (i < n) {
        unsigned o = atomicAdd(cnt, deg[i]);
        off[i] = o;
        cur[i] = o;
    }
}

__global__ void k_fill(const int* __restrict__ s, const int* __restrict__ t, int E,
                       unsigned* __restrict__ cur, int* __restrict__ col) {
    int i = blockIdx.x * blockDim.x + threadIdx.x;
    int st = gridDim.x * blockDim.x;
    for (; i < E; i += st) {
        int p = (int)atomicAdd(cur + t[i], 1u);
        col[p] = s[i];
    }
}

__global__ void k_sentinel(float* __restrict__ out, int n, float val) {
    int i = blockIdx.x * blockDim.x + threadIdx.x;
    if (i < n) out[i] = val;
}

// ---------------------------------------------------------------------------
// Packing kernels: fp16 interleaved [node][64][4], optionally pre-scaled by
// the source-side rsqrt(deg) so gather loops skip the per-edge rs lookup.
// Thread i covers (node = i>>6, lane = i&63); out elem index = i*4.
// ---------------------------------------------------------------------------

__global__ void k_pack4_scaled(const float* __restrict__ a, const float* __restrict__ b,
                               const float* __restrict__ c, const float* __restrict__ d,
                               const float* __restrict__ rs, h16* __restrict__ out, int nElem) {
    int i = blockIdx.x * blockDim.x + threadIdx.x;
    if (i >= nElem) return;
    float sc = rs[i >> 6];
    h16x4 pk;
    pk.x = (h16)(a[i] * sc);
    pk.y = (h16)(b[i] * sc);
    pk.z = (h16)(c[i] * sc);
    pk.w = (h16)(d[i] * sc);
    *reinterpret_cast<h16x4*>(out + ((size_t)i << 2)) = pk;
}

__global__ void k_pack4_plain(const float* __restrict__ a, const float* __restrict__ b,
                              const float* __restrict__ c, const float* __restrict__ d,
                              h16* __restrict__ out, int nElem) {
    int i = blockIdx.x * blockDim.x + threadIdx.x;
    if (i >= nElem) return;
    h16x4 pk;
    pk.x = (h16)a[i];
    pk.y = (h16)b[i];
    pk.z = (h16)c[i];
    pk.w = (h16)d[i];
    *reinterpret_cast<h16x4*>(out + ((size_t)i << 2)) = pk;
}

// slots 1,3 populated (cat2/cat4 pattern)
__global__ void k_pack2_13_scaled(const float* __restrict__ b, const float* __restrict__ d,
                                  const float* __restrict__ rs, h16* __restrict__ out, int nElem) {
    int i = blockIdx.x * blockDim.x + threadIdx.x;
    if (i >= nElem) return;
    float sc = rs[i >> 6];
    h16x4 pk;
    pk.x = (h16)0.f;
    pk.y = (h16)(b[i] * sc);
    pk.z = (h16)0.f;
    pk.w = (h16)(d[i] * sc);
    *reinterpret_cast<h16x4*>(out + ((size_t)i << 2)) = pk;
}

// slots 2,3 populated (city3/city4, pref3/pref4 pattern)
__global__ void k_pack2_23_scaled(const float* __restrict__ c, const float* __restrict__ d,
                                  const float* __restrict__ rs, h16* __restrict__ out, int nElem) {
    int i = blockIdx.x * blockDim.x + threadIdx.x;
    if (i >= nElem) return;
    float sc = rs[i >> 6];
    h16x4 pk;
    pk.x = (h16)0.f;
    pk.y = (h16)0.f;
    pk.z = (h16)(c[i] * sc);
    pk.w = (h16)(d[i] * sc);
    *reinterpret_cast<h16x4*>(out + ((size_t)i << 2)) = pk;
}

// ---------------------------------------------------------------------------
// Layer-1 pull kernels. One wave (64 lanes) per destination row; lane = h.
// ---------------------------------------------------------------------------

// user <- spot over us_r (all 4 branches), div=1. pk_spot UNscaled -> rs gather.
__global__ void k_l1_user(const int* __restrict__ col, const unsigned* __restrict__ off,
                          const unsigned* __restrict__ deg,
                          const float* __restrict__ rs_src, const float* __restrict__ rs_dst,
                          const h16* __restrict__ pkS,
                          h16* __restrict__ out, int n) {
    int w = (blockIdx.x * blockDim.x + threadIdx.x) >> 6;
    int lane = threadIdx.x & 63;
    if (w >= n) return;
    unsigned o = off[w], d = deg[w];
    float a0 = 0, a1 = 0, a2 = 0, a3 = 0;
    for (unsigned e = 0; e < d; ++e) {
        int s = col[o + e];
        float sc = rs_src[s];
        h16x4 v = *reinterpret_cast<const h16x4*>(pkS + s * ROW + lane * 4);
        a0 = fmaf((float)v.x, sc, a0);
        a1 = fmaf((float)v.y, sc, a1);
        a2 = fmaf((float)v.z, sc, a2);
        a3 = fmaf((float)v.w, sc, a3);
    }
    float rd = rs_dst[w];
    h16x4 pk;
    pk.x = (h16)fmaxf(a0 * rd, 0.f);
    pk.y = (h16)fmaxf(a1 * rd, 0.f);
    pk.z = (h16)fmaxf(a2 * rd, 0.f);
    pk.w = (h16)fmaxf(a3 * rd, 0.f);
    *reinterpret_cast<h16x4*>(out + w * ROW + lane * 4) = pk;
}

// spot <- user (us_f, pk_user pre-scaled) + cat (sc_r, pk_cat pre-scaled)
//       + city (sci_r, pk_city pre-scaled)
__global__ void k_l1_spot(
    const int* __restrict__ colU, const unsigned* __restrict__ offU, const unsigned* __restrict__ degU,
    const float* __restrict__ rsU_dst,
    const int* __restrict__ colC, const unsigned* __restrict__ offC, const unsigned* __restrict__ degC,
    const float* __restrict__ rsC_dst,
    const int* __restrict__ colI, const unsigned* __restrict__ offI, const unsigned* __restrict__ degI,
    const float* __restrict__ rsI_dst,
    const h16* __restrict__ pkU, const h16* __restrict__ pkC, const h16* __restrict__ pkI,
    h16* __restrict__ out, int n) {
    int w = (blockIdx.x * blockDim.x + threadIdx.x) >> 6;
    int lane = threadIdx.x & 63;
    if (w >= n) return;
    float a0 = 0, a1 = 0, a2 = 0, a3 = 0;
    {
        unsigned o = offU[w], d = degU[w];
        for (unsigned e = 0; e < d; ++e) {
            int s = colU[o + e];
            h16x4 v = *reinterpret_cast<const h16x4*>(pkU + s * ROW + lane * 4);
            a0 += (float)v.x;
            a1 += (float)v.y;
            a2 += (float)v.z;
            a3 += (float)v.w;
        }
        float rd = rsU_dst[w];
        a0 *= rd; a1 *= rd; a2 *= rd; a3 *= rd;
    }
    float cA = 0, cB = 0;
    {
        unsigned o = offC[w], d = degC[w];
        for (unsigned e = 0; e < d; ++e) {
            int s = colC[o + e];
            h16x4 v = *reinterpret_cast<const h16x4*>(pkC + s * ROW + lane * 4);
            cA += (float)v.y;
            cB += (float)v.w;
        }
        float rd = rsC_dst[w];
        cA *= rd; cB *= rd;
    }
    float iA = 0, iB = 0;
    {
        unsigned o = offI[w], d = degI[w];
        for (unsigned e = 0; e < d; ++e) {
            int s = colI[o + e];
            h16x4 v = *reinterpret_cast<const h16x4*>(pkI + s * ROW + lane * 4);
            iA += (float)v.z;
            iB += (float)v.w;
        }
        float rd = rsI_dst[w];
        iA *= rd; iB *= rd;
    }
    h16x4 pk;
    pk.x = (h16)fmaxf(a0, 0.f);
    pk.y = (h16)fmaxf((a1 + cA) * 0.5f, 0.f);
    pk.z = (h16)fmaxf((a2 + iA) * 0.5f, 0.f);
    pk.w = (h16)fmaxf((a3 + cB + iB) * (1.0f / 3.0f), 0.f);
    *reinterpret_cast<h16x4*>(out + w * ROW + lane * 4) = pk;
}

// category <- spot over sc_f (branches 2,4 -> slots 1,3). pk_spot unscaled.
__global__ void k_l1_cat(const int* __restrict__ col, const unsigned* __restrict__ off,
                         const unsigned* __restrict__ deg,
                         const float* __restrict__ rs_src, const float* __restrict__ rs_dst,
                         const h16* __restrict__ pkS,
                         h16* __restrict__ out, int n) {
    int w = (blockIdx.x * blockDim.x + threadIdx.x) >> 6;
    int lane = threadIdx.x & 63;
    if (w >= n) return;
    unsigned o = off[w], d = deg[w];
    float a1 = 0, a3 = 0;
    for (unsigned e = 0; e < d; ++e) {
        int s = col[o + e];
        float sc = rs_src[s];
        h16x4 v = *reinterpret_cast<const h16x4*>(pkS + s * ROW + lane * 4);
        a1 = fmaf((float)v.y, sc, a1);
        a3 = fmaf((float)v.w, sc, a3);
    }
    float rd = rs_dst[w];
    h16x4 pk;
    pk.x = (h16)0.f;
    pk.y = (h16)fmaxf(a1 * rd, 0.f);
    pk.z = (h16)0.f;
    pk.w = (h16)fmaxf(a3 * rd, 0.f);
    *reinterpret_cast<h16x4*>(out + w * ROW + lane * 4) = pk;
}

// city <- spot (sci_f, pk_spot unscaled) + pref (cp_r, pk_pref pre-scaled)
__global__ void k_l1_city(const int* __restrict__ colS, const unsigned* __restrict__ offS,
                          const unsigned* __restrict__ degS,
                          const float* __restrict__ rsS_src, const float* __restrict__ rsS_dst,
                          const int* __restrict__ colP, const unsigned* __restrict__ offP,
                          const unsigned* __restrict__ degP,
                          const float* __restrict__ rsP_dst,
                          const h16* __restrict__ pkS, const h16* __restrict__ pkP,
                          h16* __restrict__ out, int n) {
    int w = (blockIdx.x * blockDim.x + threadIdx.x) >> 6;
    int lane = threadIdx.x & 63;
    if (w >= n) return;
    float a2 = 0, a3 = 0;
    {
        unsigned o = offS[w], d = degS[w];
        for (unsigned e = 0; e < d; ++e) {
            int s = colS[o + e];
            float sc = rsS_src[s];
            h16x4 v = *reinterpret_cast<const h16x4*>(pkS + s * ROW + lane * 4);
            a2 = fmaf((float)v.z, sc, a2);
            a3 = fmaf((float)v.w, sc, a3);
        }
        float rd = rsS_dst[w];
        a2 *= rd; a3 *= rd;
    }
    float b2 = 0, b3 = 0;
    {
        unsigned o = offP[w], d = degP[w];
        for (unsigned e = 0; e < d; ++e) {
            int s = colP[o + e];
            h16x4 v = *reinterpret_cast<const h16x4*>(pkP + s * ROW + lane * 4);
            b2 += (float)v.z;
            b3 += (float)v.w;
        }
        float rd = rsP_dst[w];
        b2 *= rd; b3 *= rd;
    }
    h16x4 pk;
    pk.x = (h16)0.f;
    pk.y = (h16)0.f;
    pk.z = (h16)fmaxf((a2 + b2) * 0.5f, 0.f);
    pk.w = (h16)fmaxf((a3 + b3) * 0.5f, 0.f);
    *reinterpret_cast<h16x4*>(out + w * ROW + lane * 4) = pk;
}

// ---------------------------------------------------------------------------
// Layer-2 + mean-over-layers + linear head, fused. L2 never materialized.
// ---------------------------------------------------------------------------

__global__ void k_user_out(const int* __restrict__ col, const unsigned* __restrict__ off,
                           const unsigned* __restrict__ deg,
                           const float* __restrict__ rs_src, const float* __restrict__ rs_dst,
                           const h16* __restrict__ l1spot, const h16* __restrict__ l1user,
                           const float* __restrict__ x1, const float* __restrict__ x2,
                           const float* __restrict__ x3, const float* __restrict__ x4,
                           const float* __restrict__ wlin, const float* __restrict__ blin,
                           float* __restrict__ out, int n) {
    int u = (blockIdx.x * blockDim.x + threadIdx.x) >> 6;
    int lane = threadIdx.x & 63;
    if (u >= n) return;
    float a0 = 0, a1 = 0, a2 = 0, a3 = 0;
    unsigned o = off[u], d = deg[u];
    for (unsigned e = 0; e < d; ++e) {
        int s = col[o + e];
        float sc = rs_src[s];
        h16x4 v = *reinterpret_cast<const h16x4*>(l1spot + s * ROW + lane * 4);
        a0 = fmaf((float)v.x, sc, a0);
        a1 = fmaf((float)v.y, sc, a1);
        a2 = fmaf((float)v.z, sc, a2);
        a3 = fmaf((float)v.w, sc, a3);
    }
    float rd = rs_dst[u];
    a0 = fmaxf(a0 * rd, 0.f);
    a1 = fmaxf(a1 * rd, 0.f);
    a2 = fmaxf(a2 * rd, 0.f);
    a3 = fmaxf(a3 * rd, 0.f);
    int xb = u * HD + lane;
    h16x4 lv = *reinterpret_cast<const h16x4*>(l1user + u * ROW + lane * 4);
    const float third = 1.0f / 3.0f;
    float m0 = (x1[xb] + (float)lv.x + a0) * third;
    float m1 = (x2[xb] + (float)lv.y + a1) * third;
    float m2 = (x3[xb] + (float)lv.z + a2) * third;
    float m3 = (x4[xb] + (float)lv.w + a3) * third;
    float p = m0 * wlin[lane] + m1 * wlin[HD + lane] + m2 * wlin[2 * HD + lane] +
              m3 * wlin[3 * HD + lane];
#pragma unroll
    for (int ofs = 32; ofs; ofs >>= 1) p += __shfl_xor(p, ofs, 64);
    if (lane == 0) out[u] = p + blin[0];
}

__global__ void k_spot_out(
    const int* __restrict__ colU, const unsigned* __restrict__ offU, const unsigned* __restrict__ degU,
    const float* __restrict__ rsU_src, const float* __restrict__ rsU_dst,
    const int* __restrict__ colC, const unsigned* __restrict__ offC, const unsigned* __restrict__ degC,
    const float* __restrict__ rsC_src, const float* __restrict__ rsC_dst,
    const int* __restrict__ colI, const unsigned* __restrict__ offI, const unsigned* __restrict__ degI,
    const float* __restrict__ rsI_src, const float* __restrict__ rsI_dst,
    const h16* __restrict__ l1user, const h16* __restrict__ l1cat,
    const h16* __restrict__ l1city, const h16* __restrict__ l1spot,
    const float* __restrict__ x1, const float* __restrict__ x2,
    const float* __restrict__ x3, const float* __restrict__ x4,
    const float* __restrict__ wlin, const float* __restrict__ blin,
    float* __restrict__ out, int n) {
    int w = (blockIdx.x * blockDim.x + threadIdx.x) >> 6;
    int lane = threadIdx.x & 63;
    if (w >= n) return;
    float a0 = 0, a1 = 0, a2 = 0, a3 = 0;
    {
        unsigned o = offU[w], d = degU[w];
        for (unsigned e = 0; e < d; ++e) {
            int s = colU[o + e];
            float sc = rsU_src[s];
            h16x4 v = *reinterpret_cast<const h16x4*>(l1user + s * ROW + lane * 4);
            a0 = fmaf((float)v.x, sc, a0);
            a1 = fmaf((float)v.y, sc, a1);
            a2 = fmaf((float)v.z, sc, a2);
            a3 = fmaf((float)v.w, sc, a3);
        }
        float rd = rsU_dst[w];
        a0 *= rd; a1 *= rd; a2 *= rd; a3 *= rd;
    }
    float cA = 0, cB = 0;
    {
        unsigned o = offC[w], d = degC[w];
        for (unsigned e = 0; e < d; ++e) {
            int s = colC[o + e];
            float sc = rsC_src[s];
            h16x4 v = *reinterpret_cast<const h16x4*>(l1cat + s * ROW + lane * 4);
            cA = fmaf((float)v.y, sc, cA);
            cB = fmaf((float)v.w, sc, cB);
        }
        float rd = rsC_dst[w];
        cA *= rd; cB *= rd;
    }
    float iA = 0, iB = 0;
    {
        unsigned o = offI[w], d = degI[w];
        for (unsigned e = 0; e < d; ++e) {
            int s = colI[o + e];
            float sc = rsI_src[s];
            h16x4 v = *reinterpret_cast<const h16x4*>(l1city + s * ROW + lane * 4);
            iA = fmaf((float)v.z, sc, iA);
            iB = fmaf((float)v.w, sc, iB);
        }
        float rd = rsI_dst[w];
        iA *= rd; iB *= rd;
    }
    float L0 = fmaxf(a0, 0.f);
    float L1 = fmaxf((a1 + cA) * 0.5f, 0.f);
    float L2 = fmaxf((a2 + iA) * 0.5f, 0.f);
    float L3 = fmaxf((a3 + cB + iB) * (1.0f / 3.0f), 0.f);
    int xb = w * HD + lane;
    h16x4 lv = *reinterpret_cast<const h16x4*>(l1spot + w * ROW + lane * 4);
    const float third = 1.0f / 3.0f;
    float m0 = (x1[xb] + (float)lv.x + L0) * third;
    float m1 = (x2[xb] + (float)lv.y + L1) * third;
    float m2 = (x3[xb] + (float)lv.z + L2) * third;
    float m3 = (x4[xb] + (float)lv.w + L3) * third;
    float p = m0 * wlin[lane] + m1 * wlin[HD + lane] + m2 * wlin[2 * HD + lane] +
              m3 * wlin[3 * HD + lane];
#pragma unroll
    for (int ofs = 32; ofs; ofs >>= 1) p += __shfl_xor(p, ofs, 64);
    if (lane == 0) out[w] = p + blin[0];
}

// ---------------------------------------------------------------------------

static inline unsigned cdivu(unsigned a, unsigned b) { return (a + b - 1) / b; }

extern "C" void kernel_launch(void* const* d_in, const int* in_sizes, int n_in,
                              void* d_out, int out_size, void* d_ws, size_t ws_size,
                              hipStream_t stream) {
    const float* user1 = (const float*)d_in[0];
    const float* spot1 = (const float*)d_in[1];
    const float* user2 = (const float*)d_in[2];
    const float* spot2 = (const float*)d_in[3];
    const float* cat2  = (const float*)d_in[4];
    const float* user3 = (const float*)d_in[5];
    const float* spot3 = (const float*)d_in[6];
    const float* city3 = (const float*)d_in[7];
    const float* pref3 = (const float*)d_in[8];
    const float* user4 = (const float*)d_in[9];
    const float* spot4 = (const float*)d_in[10];
    const float* city4 = (const float*)d_in[11];
    const float* pref4 = (const float*)d_in[12];
    const float* cat4  = (const float*)d_in[13];
    const float* w_user = (const float*)d_in[14];
    const float* b_user = (const float*)d_in[15];
    const float* w_spot = (const float*)d_in[16];
    const float* b_spot = (const float*)d_in[17];
    const int* us_src  = (const int*)d_in[18];
    const int* us_dst  = (const int*)d_in[19];
    const int* sc_src  = (const int*)d_in[20];
    const int* sc_dst  = (const int*)d_in[21];
    const int* sci_src = (const int*)d_in[22];
    const int* sci_dst = (const int*)d_in[23];
    const int* cp_src  = (const int*)d_in[24];
    const int* cp_dst  = (const int*)d_in[25];

    const int NU = in_sizes[0] / HD, NS = in_sizes[1] / HD, NC = in_sizes[4] / HD;
    const int NCI = in_sizes[7] / HD, NP = in_sizes[8] / HD;
    const int EUS = in_sizes[18], ESC = in_sizes[20], ESCI = in_sizes[22], ECP = in_sizes[24];

    // ---- workspace bump allocator (256B aligned) ----
    char* wp = (char*)d_ws;
    auto alloc = [&](size_t bytes) -> void* {
        void* r = (void*)wp;
        wp += (bytes + 255) & ~(size_t)255;
        return r;
    };

    // degree block: 8 arrays + 7 counters, contiguous -> single memset
    const size_t nDeg = (size_t)NU + NS + NS + NC + NS + NCI + NCI + NP;
    unsigned* degBase = (unsigned*)alloc((nDeg + 8) * sizeof(unsigned));
    unsigned* ds_u   = degBase;                 // us: src user deg
    unsigned* dt_s   = ds_u + NU;               // us: dst spot deg
    unsigned* ds_ssc = dt_s + NS;               // sc: src spot deg
    unsigned* dt_c   = ds_ssc + NS;             // sc: dst cat deg
    unsigned* ds_ssi = dt_c + NC;               // sci: src spot deg
    unsigned* dt_ci  = ds_ssi + NS;             // sci: dst city deg
    unsigned* ds_cic = dt_ci + NCI;             // cp: src city deg
    unsigned* dt_p   = ds_cic + NCI;            // cp: dst pref deg
    unsigned* cnt    = dt_p + NP;               // 7 counters (padded to 8)

    float* rsBase = (float*)alloc(nDeg * sizeof(float));
    float* rs_ds_u   = rsBase;
    float* rs_dt_s   = rs_ds_u + NU;
    float* rs_ds_ssc = rs_dt_s + NS;
    float* rs_dt_c   = rs_ds_ssc + NS;
    float* rs_ds_ssi = rs_dt_c + NC;
    float* rs_dt_ci  = rs_ds_ssi + NS;
    float* rs_ds_cic = rs_dt_ci + NCI;
    float* rs_dt_p   = rs_ds_cic + NCI;

    // CSR offset/cursor/col arrays for the 7 needed pull directions
    unsigned* off_usf = (unsigned*)alloc(NS * 4);  unsigned* cur_usf = (unsigned*)alloc(NS * 4);
    unsigned* off_usr = (unsigned*)alloc((size_t)NU * 4); unsigned* cur_usr = (unsigned*)alloc((size_t)NU * 4);
    unsigned* off_scf = (unsigned*)alloc(NC * 4);  unsigned* cur_scf = (unsigned*)alloc(NC * 4);
    unsigned* off_scr = (unsigned*)alloc(NS * 4);  unsigned* cur_scr = (unsigned*)alloc(NS * 4);
    unsigned* off_sif = (unsigned*)alloc(NCI * 4); unsigned* cur_sif = (unsigned*)alloc(NCI * 4);
    unsigned* off_sir = (unsigned*)alloc(NS * 4);  unsigned* cur_sir = (unsigned*)alloc(NS * 4);
    unsigned* off_cpr = (unsigned*)alloc(NCI * 4); unsigned* cur_cpr = (unsigned*)alloc(NCI * 4);
    int* col_usf = (int*)alloc((size_t)EUS * 4);
    int* col_usr = (int*)alloc((size_t)EUS * 4);
    int* col_scf = (int*)alloc((size_t)ESC * 4);
    int* col_scr = (int*)alloc((size_t)ESC * 4);
    int* col_sif = (int*)alloc((size_t)ESCI * 4);
    int* col_sir = (int*)alloc((size_t)ESCI * 4);
    int* col_cpr = (int*)alloc((size_t)ECP * 4);

    // fp16 packed tables [node][64][4]
    h16* pk_user = (h16*)alloc((size_t)NU * ROW * 2);   // pre-scaled by rs_ds_u; ALIASED as l1_user later
    h16* pk_spot = (h16*)alloc((size_t)NS * ROW * 2);   // unscaled (3 consumers, different scales)
    h16* pk_cat  = (h16*)alloc((size_t)NC * ROW * 2);   // pre-scaled by rs_dt_c
    h16* pk_city = (h16*)alloc((size_t)NCI * ROW * 2);  // pre-scaled by rs_dt_ci
    h16* pk_pref = (h16*)alloc((size_t)NP * ROW * 2);   // pre-scaled by rs_dt_p

    // L1 feature planes (l1_user aliases pk_user: k_l1_spot, pk_user's only
    // consumer, runs before k_l1_user on the same stream)
    h16* l1_user = pk_user;
    h16* l1_spot = (h16*)alloc((size_t)NS * ROW * 2);
    h16* l1_cat  = (h16*)alloc((size_t)NC * ROW * 2);
    h16* l1_city = (h16*)alloc((size_t)NCI * ROW * 2);

    float* outU = (float*)d_out;
    float* outS = outU + NU;

    // ---- ws guard: if workspace too small, emit readable sentinel, no ws writes
    size_t need = (size_t)(wp - (char*)d_ws);
    if (need > ws_size) {
        float val = 1000.0f + (float)(ws_size >> 20);
        k_sentinel<<<cdivu((unsigned)out_size, 256), 256, 0, stream>>>((float*)d_out, out_size, val);
        return;
    }

    // ---- build degrees / norms / CSRs ----
    hipMemsetAsync(degBase, 0, (nDeg + 8) * sizeof(unsigned), stream);
    k_count<<<1024, 256, 0, stream>>>(us_src, us_dst, EUS, ds_u, dt_s);
    k_count<<<256, 256, 0, stream>>>(sc_src, sc_dst, ESC, ds_ssc, dt_c);
    k_count<<<256, 256, 0, stream>>>(sci_src, sci_dst, ESCI, ds_ssi, dt_ci);
    k_count<<<32, 256, 0, stream>>>(cp_src, cp_dst, ECP, ds_cic, dt_p);
    k_rs<<<cdivu((unsigned)nDeg, 256), 256, 0, stream>>>(degBase, rsBase, (int)nDeg);

    k_off<<<cdivu(NS, 256), 256, 0, stream>>>(dt_s, NS, off_usf, cur_usf, cnt + 0);
    k_off<<<cdivu(NU, 256), 256, 0, stream>>>(ds_u, NU, off_usr, cur_usr, cnt + 1);
    k_off<<<cdivu(NC, 256), 256, 0, stream>>>(dt_c, NC, off_scf, cur_scf, cnt + 2);
    k_off<<<cdivu(NS, 256), 256, 0, stream>>>(ds_ssc, NS, off_scr, cur_scr, cnt + 3);
    k_off<<<cdivu(NCI, 256), 256, 0, stream>>>(dt_ci, NCI, off_sif, cur_sif, cnt + 4);
    k_off<<<cdivu(NS, 256), 256, 0, stream>>>(ds_ssi, NS, off_sir, cur_sir, cnt + 5);
    k_off<<<cdivu(NCI, 256), 256, 0, stream>>>(ds_cic, NCI, off_cpr, cur_cpr, cnt + 6);

    k_fill<<<1024, 256, 0, stream>>>(us_src, us_dst, EUS, cur_usf, col_usf);  // spot <- user
    k_fill<<<1024, 256, 0, stream>>>(us_dst, us_src, EUS, cur_usr, col_usr);  // user <- spot
    k_fill<<<256, 256, 0, stream>>>(sc_src, sc_dst, ESC, cur_scf, col_scf);   // cat  <- spot
    k_fill<<<256, 256, 0, stream>>>(sc_dst, sc_src, ESC, cur_scr, col_scr);   // spot <- cat
    k_fill<<<256, 256, 0, stream>>>(sci_src, sci_dst, ESCI, cur_sif, col_sif);// city <- spot
    k_fill<<<256, 256, 0, stream>>>(sci_dst, sci_src, ESCI, cur_sir, col_sir);// spot <- city
    k_fill<<<32, 256, 0, stream>>>(cp_dst, cp_src, ECP, cur_cpr, col_cpr);    // city <- pref

    // ---- pack fp16 interleaved tables ----
    k_pack4_scaled<<<cdivu(NU * HD, 256), 256, 0, stream>>>(
        user1, user2, user3, user4, rs_ds_u, pk_user, NU * HD);
    k_pack4_plain<<<cdivu(NS * HD, 256), 256, 0, stream>>>(
        spot1, spot2, spot3, spot4, pk_spot, NS * HD);
    k_pack2_13_scaled<<<cdivu(NC * HD, 256), 256, 0, stream>>>(
        cat2, cat4, rs_dt_c, pk_cat, NC * HD);
    k_pack2_23_scaled<<<cdivu(NCI * HD, 256), 256, 0, stream>>>(
        city3, city4, rs_dt_ci, pk_city, NCI * HD);
    k_pack2_23_scaled<<<cdivu(NP * HD, 256), 256, 0, stream>>>(
        pref3, pref4, rs_dt_p, pk_pref, NP * HD);

    // ---- layer 1 (k_l1_spot FIRST: it is pk_user's only consumer, and
    //      k_l1_user overwrites that buffer with l1_user) ----
    k_l1_spot<<<cdivu(NS, 4), 256, 0, stream>>>(
        col_usf, off_usf, dt_s, rs_dt_s,
        col_scr, off_scr, ds_ssc, rs_ds_ssc,
        col_sir, off_sir, ds_ssi, rs_ds_ssi,
        pk_user, pk_cat, pk_city, l1_spot, NS);
    k_l1_cat<<<cdivu(NC, 4), 256, 0, stream>>>(
        col_scf, off_scf, dt_c, rs_ds_ssc, rs_dt_c, pk_spot, l1_cat, NC);
    k_l1_city<<<cdivu(NCI, 4), 256, 0, stream>>>(
        col_sif, off_sif, dt_ci, rs_ds_ssi, rs_dt_ci,
        col_cpr, off_cpr, ds_cic, rs_ds_cic,
        pk_spot, pk_pref, l1_city, NCI);
    k_l1_user<<<cdivu(NU, 4), 256, 0, stream>>>(
        col_usr, off_usr, ds_u, rs_dt_s, rs_ds_u,
        pk_spot, l1_user, NU);

    // ---- layer 2 fused with mean + linear head ----
    k_user_out<<<cdivu(NU, 4), 256, 0, stream>>>(
        col_usr, off_usr, ds_u, rs_dt_s, rs_ds_u,
        l1_spot, l1_user, user1, user2, user3, user4,
        w_user, b_user, outU, NU);
    k_spot_out<<<cdivu(NS, 4), 256, 0, stream>>>(
        col_usf, off_usf, dt_s, rs_ds_u, rs_dt_s,
        col_scr, off_scr, ds_ssc, rs_dt_c, rs_ds_ssc,
        col_sir, off_sir, ds_ssi, rs_dt_ci, rs_ds_ssi,
        l1_user, l1_cat, l1_city, l1_spot,
        spot1, spot2, spot3, spot4,
        w_spot, b_spot, outS, NS);

    (void)n_in; (void)out_size; (void)ws_size; (void)NP;
}